// Round 5
// baseline (955.215 us; speedup 1.0000x reference)
//
#include <hip/hip_runtime.h>
#include <stdint.h>

#define NN    100000
#define FIN   128
#define HIDN  64
#define NCLS  40
#define NE    1600000
#define NBUCK ((NN + 255) / 256)   // 391 buckets of 256 nodes
#define BCAP  8192                 // >> max bucket size (mean 4096, sd 64)

typedef unsigned int uint32;

// ---- edge dtype probe: int64 (odd u32 words all zero) vs int32 ----
__global__ __launch_bounds__(64) void probe_kernel(const unsigned int* __restrict__ raw,
                                                   int* __restrict__ flag) {
  if (threadIdx.x == 0) {
    int is64 = 1;
    for (int i = 0; i < 64; ++i)
      if (raw[2 * i + 1] != 0u) { is64 = 0; break; }
    *flag = is64;
  }
}

// ---- partition edges into dst-buckets; payload = src | (d_low8 << 17) ----
__global__ __launch_bounds__(256) void part_kernel(const void* __restrict__ eptr,
                                                   const int* __restrict__ flag,
                                                   int* __restrict__ bcnt,
                                                   uint32* __restrict__ bbuf) {
  int e = blockIdx.x * 256 + threadIdx.x;
  int s, d;
  if (*flag) {
    const long long* p = (const long long*)eptr;
    s = (int)p[e]; d = (int)p[e + NE];
  } else {
    const int* p = (const int*)eptr;
    s = p[e]; d = p[e + NE];
  }
  int b = d >> 8;
  int slot = atomicAdd(&bcnt[b], 1);
  if (slot < BCAP)  // statistically impossible to overflow (24+ sigma)
    bbuf[(size_t)b * BCAP + slot] = (uint32)s | ((uint32)(d & 255) << 17);
}

// ---- exclusive scan of bucket counts -> bucket base offsets ----
__global__ __launch_bounds__(512) void bscan_kernel(const int* __restrict__ bcnt,
                                                    int* __restrict__ bbase) {
  __shared__ int s[512];
  int i = threadIdx.x;
  int v = (i < NBUCK) ? min(bcnt[i], BCAP) : 0;
  s[i] = v;
  __syncthreads();
#pragma unroll
  for (int d = 1; d < 512; d <<= 1) {
    int t = (i >= d) ? s[i - d] : 0;
    __syncthreads();
    s[i] += t;
    __syncthreads();
  }
  if (i < NBUCK) bbase[i] = s[i] - v;
  if (i == NBUCK - 1) bbase[NBUCK] = s[i];
}

// ---- per-bucket CSR build: LDS hist + scan + rank placement ----
__global__ __launch_bounds__(256) void build_kernel(const int* __restrict__ bcnt,
                                                    const int* __restrict__ bbase,
                                                    const uint32* __restrict__ bbuf,
                                                    int* __restrict__ off,
                                                    float* __restrict__ dinv,
                                                    int* __restrict__ s_src) {
  __shared__ int hist[256];
  __shared__ int lofs[256];
  __shared__ int rank[256];
  int b = blockIdx.x, tid = threadIdx.x;
  int count = min(bcnt[b], BCAP);
  const uint32* p = bbuf + (size_t)b * BCAP;
  hist[tid] = 0;
  __syncthreads();
  for (int i = tid; i < count; i += 256) atomicAdd(&hist[p[i] >> 17], 1);
  __syncthreads();
  int deg = hist[tid];
  lofs[tid] = deg;
  __syncthreads();
#pragma unroll
  for (int dd = 1; dd < 256; dd <<= 1) {
    int t = (tid >= dd) ? lofs[tid - dd] : 0;
    __syncthreads();
    lofs[tid] += t;
    __syncthreads();
  }
  int excl = lofs[tid] - deg;
  __syncthreads();
  lofs[tid] = excl;
  rank[tid] = 0;
  int base = bbase[b];
  int n = b * 256 + tid;
  if (n < NN) {
    off[n] = base + excl;
    dinv[n] = rsqrtf((float)deg + 1.0f);
  }
  if (b == 0 && tid == 0) off[NN] = NE;
  __syncthreads();
  for (int i = tid; i < count; i += 256) {
    uint32 v = p[i];
    int dl = (int)(v >> 17);
    int s = (int)(v & 0x1FFFFu);
    int r = atomicAdd(&rank[dl], 1);
    s_src[base + lofs[dl] + r] = s;
  }
}

// ---- GEMM1: h[N,64](fp32) = (x[N,128] @ W1[128,64]) * dinv[row] ----
__global__ __launch_bounds__(256) void gemm1_kernel(const float* __restrict__ x,
                                                    const float* __restrict__ W,
                                                    const float* __restrict__ dinv,
                                                    float* __restrict__ h) {
  __shared__ float sW[FIN * HIDN];  // 32 KB
  int tid = threadIdx.x;
  {
    const float4* W4 = (const float4*)W;
    float4* sW4 = (float4*)sW;
#pragma unroll
    for (int i = 0; i < 8; ++i) sW4[i * 256 + tid] = W4[i * 256 + tid];
  }
  __syncthreads();
  int cg = tid & 3;
  int rp = tid >> 2;
  int r0 = blockIdx.x * 128 + rp * 2;
  int r1 = r0 + 1;
  bool v0 = (r0 < NN), v1 = (r1 < NN);
  int c0 = cg * 16;
  float4 a0[4], a1[4];
#pragma unroll
  for (int j = 0; j < 4; ++j) {
    a0[j] = make_float4(0.f, 0.f, 0.f, 0.f);
    a1[j] = make_float4(0.f, 0.f, 0.f, 0.f);
  }
  const float4* x4 = (const float4*)x;
  const float4 z4 = make_float4(0.f, 0.f, 0.f, 0.f);
  for (int k0 = 0; k0 < FIN; k0 += 4) {
    float4 xa = v0 ? x4[(size_t)r0 * 32 + (k0 >> 2)] : z4;
    float4 xb = v1 ? x4[(size_t)r1 * 32 + (k0 >> 2)] : z4;
#pragma unroll
    for (int kk = 0; kk < 4; ++kk) {
      float xav = (&xa.x)[kk];
      float xbv = (&xb.x)[kk];
      int k = k0 + kk;
#pragma unroll
      for (int j = 0; j < 4; ++j) {
        float4 wv = *(const float4*)&sW[k * HIDN + c0 + 4 * j];
        a0[j].x += xav * wv.x; a0[j].y += xav * wv.y;
        a0[j].z += xav * wv.z; a0[j].w += xav * wv.w;
        a1[j].x += xbv * wv.x; a1[j].y += xbv * wv.y;
        a1[j].z += xbv * wv.z; a1[j].w += xbv * wv.w;
      }
    }
  }
  if (v0) {
    float di = dinv[r0];
    float4* hp = (float4*)&h[(size_t)r0 * HIDN + c0];
#pragma unroll
    for (int j = 0; j < 4; ++j) {
      float4 q = a0[j];
      q.x *= di; q.y *= di; q.z *= di; q.w *= di;
      hp[j] = q;
    }
  }
  if (v1) {
    float di = dinv[r1];
    float4* hp = (float4*)&h[(size_t)r1 * HIDN + c0];
#pragma unroll
    for (int j = 0; j < 4; ++j) {
      float4 q = a1[j];
      q.x *= di; q.y *= di; q.z *= di; q.w *= di;
      hp[j] = q;
    }
  }
}

// ---- agg1: agg[n,c] = dinv[n]*(h[n,c] + sum_j h[s_j,c]) + b1[c] ----
__global__ __launch_bounds__(256) void agg1_kernel(const int* __restrict__ off,
                                                   const int* __restrict__ s_src,
                                                   const float* __restrict__ h,
                                                   const float* __restrict__ dinv,
                                                   const float* __restrict__ b1,
                                                   float* __restrict__ agg) {
  int t = blockIdx.x * 256 + threadIdx.x;
  int n = t >> 6, c = t & 63;
  int j0 = off[n], j1 = off[n + 1];
  float acc = h[(size_t)n * HIDN + c];
  int j = j0;
  for (; j + 1 < j1; j += 2) {
    int s0 = s_src[j], s1 = s_src[j + 1];
    acc += h[(size_t)s0 * HIDN + c];
    acc += h[(size_t)s1 * HIDN + c];
  }
  if (j < j1) acc += h[(size_t)s_src[j] * HIDN + c];
  agg[(size_t)n * HIDN + c] = acc * dinv[n] + b1[c];
}

// ---- GEMM2: h2[N,40](fp32) = (relu(agg)[N,64] @ W2[64,40]) * dinv[row] ----
__global__ __launch_bounds__(320) void gemm2_kernel(const float* __restrict__ agg,
                                                    const float* __restrict__ W2,
                                                    const float* __restrict__ dinv,
                                                    float* __restrict__ h2) {
  __shared__ float sW[HIDN * NCLS];  // 10 KB
  int tid = threadIdx.x;
  for (int i = tid; i < (HIDN * NCLS) / 4; i += 320)
    ((float4*)sW)[i] = ((const float4*)W2)[i];
  __syncthreads();
  int cg = tid % 10;
  int rp = tid / 10;
  int r0 = blockIdx.x * 64 + rp * 2;
  int r1 = r0 + 1;
  bool v0 = (r0 < NN), v1 = (r1 < NN);
  int c0 = cg * 4;
  float4 a0 = make_float4(0.f, 0.f, 0.f, 0.f);
  float4 a1 = make_float4(0.f, 0.f, 0.f, 0.f);
  const float4* g4 = (const float4*)agg;
  const float4 z4 = make_float4(0.f, 0.f, 0.f, 0.f);
  for (int k0 = 0; k0 < HIDN; k0 += 4) {
    float4 xa = v0 ? g4[(size_t)r0 * 16 + (k0 >> 2)] : z4;
    float4 xb = v1 ? g4[(size_t)r1 * 16 + (k0 >> 2)] : z4;
    xa.x = fmaxf(xa.x, 0.f); xa.y = fmaxf(xa.y, 0.f);
    xa.z = fmaxf(xa.z, 0.f); xa.w = fmaxf(xa.w, 0.f);
    xb.x = fmaxf(xb.x, 0.f); xb.y = fmaxf(xb.y, 0.f);
    xb.z = fmaxf(xb.z, 0.f); xb.w = fmaxf(xb.w, 0.f);
#pragma unroll
    for (int kk = 0; kk < 4; ++kk) {
      float xav = (&xa.x)[kk];
      float xbv = (&xb.x)[kk];
      float4 wv = *(const float4*)&sW[(k0 + kk) * NCLS + c0];
      a0.x += xav * wv.x; a0.y += xav * wv.y; a0.z += xav * wv.z; a0.w += xav * wv.w;
      a1.x += xbv * wv.x; a1.y += xbv * wv.y; a1.z += xbv * wv.z; a1.w += xbv * wv.w;
    }
  }
  if (v0) {
    float di = dinv[r0];
    a0.x *= di; a0.y *= di; a0.z *= di; a0.w *= di;
    *(float4*)&h2[(size_t)r0 * NCLS + c0] = a0;
  }
  if (v1) {
    float di = dinv[r1];
    a1.x *= di; a1.y *= di; a1.z *= di; a1.w *= di;
    *(float4*)&h2[(size_t)r1 * NCLS + c0] = a1;
  }
}

// ---- agg2: out[n,c] = dinv[n]*(h2[n,c] + sum_j h2[s_j,c]) + b2[c] ----
__global__ __launch_bounds__(256) void agg2_kernel(const int* __restrict__ off,
                                                   const int* __restrict__ s_src,
                                                   const float* __restrict__ h2,
                                                   const float* __restrict__ dinv,
                                                   const float* __restrict__ b2,
                                                   float* __restrict__ out) {
  unsigned t = blockIdx.x * 256 + threadIdx.x;
  unsigned n = t / NCLS;
  unsigned c = t - n * NCLS;
  if (n >= NN) return;
  int j0 = off[n], j1 = off[n + 1];
  float acc = h2[(size_t)n * NCLS + c];
  int j = j0;
  for (; j + 1 < j1; j += 2) {
    int s0 = s_src[j], s1 = s_src[j + 1];
    acc += h2[(size_t)s0 * NCLS + c];
    acc += h2[(size_t)s1 * NCLS + c];
  }
  if (j < j1) acc += h2[(size_t)s_src[j] * NCLS + c];
  out[(size_t)n * NCLS + c] = acc * dinv[n] + b2[c];
}

extern "C" void kernel_launch(void* const* d_in, const int* in_sizes, int n_in,
                              void* d_out, int out_size, void* d_ws, size_t ws_size,
                              hipStream_t stream) {
  const float* x  = (const float*)d_in[0];
  const void*  ei = d_in[1];
  const float* W1 = (const float*)d_in[2];
  const float* b1 = (const float*)d_in[3];
  const float* W2 = (const float*)d_in[4];
  const float* b2 = (const float*)d_in[5];
  float* out = (float*)d_out;

  char* w = (char*)d_ws;
  size_t off_b = 0;
  auto carve = [&](size_t bytes) -> void* {
    void* p = w + off_b;
    off_b = (off_b + bytes + 255) & ~(size_t)255;
    return p;
  };
  int*   bcnt  = (int*)  carve((size_t)NBUCK * 4);
  int*   bbase = (int*)  carve((size_t)(NBUCK + 1) * 4);
  int*   offs  = (int*)  carve((size_t)(NN + 1) * 4);
  float* dinv  = (float*)carve((size_t)NN * 4);
  int*   flag  = (int*)  carve(256);
  int*   s_src = (int*)  carve((size_t)NE * 4);
  float* h     = (float*)carve((size_t)NN * HIDN * 4);   // also reused as h2
  float* agg   = (float*)carve((size_t)NN * HIDN * 4);   // also holds bbuf first
  // aliases: bbuf lives in agg's region (dead before agg1 writes agg);
  //          h2 lives in h's region (h dead after agg1 reads it)
  uint32* bbuf = (uint32*)agg;   // NBUCK*BCAP*4 = 12.8 MB <= 25.6 MB
  float*  h2   = h;              // 16 MB <= 25.6 MB

  probe_kernel<<<1, 64, 0, stream>>>((const unsigned int*)ei, flag);
  hipMemsetAsync(bcnt, 0, (size_t)NBUCK * 4, stream);
  part_kernel<<<NE / 256, 256, 0, stream>>>(ei, flag, bcnt, bbuf);
  bscan_kernel<<<1, 512, 0, stream>>>(bcnt, bbase);
  build_kernel<<<NBUCK, 256, 0, stream>>>(bcnt, bbase, bbuf, offs, dinv, s_src);
  gemm1_kernel<<<(NN + 127) / 128, 256, 0, stream>>>(x, W1, dinv, h);
  agg1_kernel<<<(NN * HIDN) / 256, 256, 0, stream>>>(offs, s_src, h, dinv, b1, agg);
  gemm2_kernel<<<(NN + 63) / 64, 320, 0, stream>>>(agg, W2, dinv, h2);
  agg2_kernel<<<(NN * NCLS + 255) / 256, 256, 0, stream>>>(offs, s_src, h2, dinv, b2, out);
}

// Round 6
// 418.398 us; speedup vs baseline: 2.2830x; 2.2830x over previous
//
#include <hip/hip_runtime.h>
#include <stdint.h>

#define NN    100000
#define FIN   128
#define HIDN  64
#define NCLS  40
#define NE    1600000
#define NBUCK ((NN + 255) / 256)      // 391 buckets of 256 nodes
#define EPB   4096                    // edges per partition block
#define NEB   ((NE + EPB - 1) / EPB)  // 391 partition blocks

typedef unsigned int uint32;

// ---- edge dtype probe: int64 (odd u32 words all zero) vs int32 ----
__global__ __launch_bounds__(64) void probe_kernel(const unsigned int* __restrict__ raw,
                                                   int* __restrict__ flag) {
  if (threadIdx.x == 0) {
    int is64 = 1;
    for (int i = 0; i < 64; ++i)
      if (raw[2 * i + 1] != 0u) { is64 = 0; break; }
    *flag = is64;
  }
}

// ---- passA: per-block bucket histogram -> mat[blk][bucket] ----
__global__ __launch_bounds__(256) void passA_kernel(const void* __restrict__ eptr,
                                                    const int* __restrict__ flag,
                                                    int* __restrict__ mat) {
  __shared__ int cnt[NBUCK];
  int tid = threadIdx.x;
  for (int i = tid; i < NBUCK; i += 256) cnt[i] = 0;
  __syncthreads();
  int is64 = *flag;
  int base = blockIdx.x * EPB;
#pragma unroll
  for (int k = 0; k < EPB / 256; ++k) {
    int e = base + k * 256 + tid;
    if (e < NE) {
      int d = is64 ? (int)((const long long*)eptr)[e + NE]
                   : ((const int*)eptr)[e + NE];
      atomicAdd(&cnt[d >> 8], 1);
    }
  }
  __syncthreads();
  for (int i = tid; i < NBUCK; i += 256)
    mat[blockIdx.x * NBUCK + i] = cnt[i];
}

// ---- passB1: per-bucket exclusive scan over blocks; emit bucket totals ----
__global__ __launch_bounds__(512) void passB1_kernel(int* __restrict__ mat,
                                                     int* __restrict__ tot) {
  __shared__ int s[512];
  int b = blockIdx.x;         // bucket
  int t = threadIdx.x;        // block index
  int v = (t < NEB) ? mat[t * NBUCK + b] : 0;
  s[t] = v;
  __syncthreads();
#pragma unroll
  for (int d = 1; d < 512; d <<= 1) {
    int u = (t >= d) ? s[t - d] : 0;
    __syncthreads();
    s[t] += u;
    __syncthreads();
  }
  if (t < NEB) mat[t * NBUCK + b] = s[t] - v;  // exclusive prefix within bucket
  if (t == 511) tot[b] = s[511];
}

// ---- passB2: exclusive scan of bucket totals -> bbase ----
__global__ __launch_bounds__(512) void passB2_kernel(const int* __restrict__ tot,
                                                     int* __restrict__ bbase) {
  __shared__ int s[512];
  int i = threadIdx.x;
  int v = (i < NBUCK) ? tot[i] : 0;
  s[i] = v;
  __syncthreads();
#pragma unroll
  for (int d = 1; d < 512; d <<= 1) {
    int u = (i >= d) ? s[i - d] : 0;
    __syncthreads();
    s[i] += u;
    __syncthreads();
  }
  if (i < NBUCK) bbase[i] = s[i] - v;
  if (i == 511) bbase[NBUCK] = s[511];
}

// ---- passC: place edges into compact bucket-sorted bbuf (LDS cursors) ----
__global__ __launch_bounds__(256) void passC_kernel(const void* __restrict__ eptr,
                                                    const int* __restrict__ flag,
                                                    const int* __restrict__ mat,
                                                    const int* __restrict__ bbase,
                                                    uint32* __restrict__ bbuf) {
  __shared__ int cur[NBUCK];
  int tid = threadIdx.x;
  for (int i = tid; i < NBUCK; i += 256)
    cur[i] = bbase[i] + mat[blockIdx.x * NBUCK + i];
  __syncthreads();
  int is64 = *flag;
  int base = blockIdx.x * EPB;
#pragma unroll
  for (int k = 0; k < EPB / 256; ++k) {
    int e = base + k * 256 + tid;
    if (e < NE) {
      int s, d;
      if (is64) {
        const long long* p = (const long long*)eptr;
        s = (int)p[e]; d = (int)p[e + NE];
      } else {
        const int* p = (const int*)eptr;
        s = p[e]; d = p[e + NE];
      }
      int slot = atomicAdd(&cur[d >> 8], 1);
      bbuf[slot] = (uint32)s | ((uint32)(d & 255) << 17);
    }
  }
}

// ---- build: per-bucket CSR (LDS hist + scan + rank placement) ----
__global__ __launch_bounds__(256) void build_kernel(const int* __restrict__ bbase,
                                                    const uint32* __restrict__ bbuf,
                                                    int* __restrict__ off,
                                                    float* __restrict__ dinv,
                                                    int* __restrict__ s_src) {
  __shared__ int hist[256];
  __shared__ int lofs[256];
  __shared__ int rank[256];
  int b = blockIdx.x, tid = threadIdx.x;
  int base = bbase[b];
  int count = bbase[b + 1] - base;
  const uint32* p = bbuf + base;
  hist[tid] = 0;
  __syncthreads();
  for (int i = tid; i < count; i += 256) atomicAdd(&hist[p[i] >> 17], 1);
  __syncthreads();
  int deg = hist[tid];
  lofs[tid] = deg;
  __syncthreads();
#pragma unroll
  for (int dd = 1; dd < 256; dd <<= 1) {
    int t = (tid >= dd) ? lofs[tid - dd] : 0;
    __syncthreads();
    lofs[tid] += t;
    __syncthreads();
  }
  int excl = lofs[tid] - deg;
  __syncthreads();
  lofs[tid] = excl;
  rank[tid] = 0;
  int n = b * 256 + tid;
  if (n < NN) {
    off[n] = base + excl;
    dinv[n] = rsqrtf((float)deg + 1.0f);
  }
  if (b == 0 && tid == 0) off[NN] = NE;
  __syncthreads();
  for (int i = tid; i < count; i += 256) {
    uint32 v = p[i];
    int dl = (int)(v >> 17);
    int s = (int)(v & 0x1FFFFu);
    int r = atomicAdd(&rank[dl], 1);
    s_src[base + lofs[dl] + r] = s;
  }
}

// ---- GEMM1: h[N,64](fp32) = (x[N,128] @ W1[128,64]) * dinv[row] ----
__global__ __launch_bounds__(256) void gemm1_kernel(const float* __restrict__ x,
                                                    const float* __restrict__ W,
                                                    const float* __restrict__ dinv,
                                                    float* __restrict__ h) {
  __shared__ float sW[FIN * HIDN];  // 32 KB
  int tid = threadIdx.x;
  {
    const float4* W4 = (const float4*)W;
    float4* sW4 = (float4*)sW;
#pragma unroll
    for (int i = 0; i < 8; ++i) sW4[i * 256 + tid] = W4[i * 256 + tid];
  }
  __syncthreads();
  int cg = tid & 3;
  int rp = tid >> 2;
  int r0 = blockIdx.x * 128 + rp * 2;
  int r1 = r0 + 1;
  bool v0 = (r0 < NN), v1 = (r1 < NN);
  int c0 = cg * 16;
  float4 a0[4], a1[4];
#pragma unroll
  for (int j = 0; j < 4; ++j) {
    a0[j] = make_float4(0.f, 0.f, 0.f, 0.f);
    a1[j] = make_float4(0.f, 0.f, 0.f, 0.f);
  }
  const float4* x4 = (const float4*)x;
  const float4 z4 = make_float4(0.f, 0.f, 0.f, 0.f);
  for (int k0 = 0; k0 < FIN; k0 += 4) {
    float4 xa = v0 ? x4[(size_t)r0 * 32 + (k0 >> 2)] : z4;
    float4 xb = v1 ? x4[(size_t)r1 * 32 + (k0 >> 2)] : z4;
#pragma unroll
    for (int kk = 0; kk < 4; ++kk) {
      float xav = (&xa.x)[kk];
      float xbv = (&xb.x)[kk];
      int k = k0 + kk;
#pragma unroll
      for (int j = 0; j < 4; ++j) {
        float4 wv = *(const float4*)&sW[k * HIDN + c0 + 4 * j];
        a0[j].x += xav * wv.x; a0[j].y += xav * wv.y;
        a0[j].z += xav * wv.z; a0[j].w += xav * wv.w;
        a1[j].x += xbv * wv.x; a1[j].y += xbv * wv.y;
        a1[j].z += xbv * wv.z; a1[j].w += xbv * wv.w;
      }
    }
  }
  if (v0) {
    float di = dinv[r0];
    float4* hp = (float4*)&h[(size_t)r0 * HIDN + c0];
#pragma unroll
    for (int j = 0; j < 4; ++j) {
      float4 q = a0[j];
      q.x *= di; q.y *= di; q.z *= di; q.w *= di;
      hp[j] = q;
    }
  }
  if (v1) {
    float di = dinv[r1];
    float4* hp = (float4*)&h[(size_t)r1 * HIDN + c0];
#pragma unroll
    for (int j = 0; j < 4; ++j) {
      float4 q = a1[j];
      q.x *= di; q.y *= di; q.z *= di; q.w *= di;
      hp[j] = q;
    }
  }
}

// ---- agg1: agg[n,c] = dinv[n]*(h[n,c] + sum_j h[s_j,c]) + b1[c] ----
__global__ __launch_bounds__(256) void agg1_kernel(const int* __restrict__ off,
                                                   const int* __restrict__ s_src,
                                                   const float* __restrict__ h,
                                                   const float* __restrict__ dinv,
                                                   const float* __restrict__ b1,
                                                   float* __restrict__ agg) {
  int t = blockIdx.x * 256 + threadIdx.x;
  int n = t >> 6, c = t & 63;
  int j0 = off[n], j1 = off[n + 1];
  float acc = h[(size_t)n * HIDN + c];
  int j = j0;
  for (; j + 1 < j1; j += 2) {
    int s0 = s_src[j], s1 = s_src[j + 1];
    acc += h[(size_t)s0 * HIDN + c];
    acc += h[(size_t)s1 * HIDN + c];
  }
  if (j < j1) acc += h[(size_t)s_src[j] * HIDN + c];
  agg[(size_t)n * HIDN + c] = acc * dinv[n] + b1[c];
}

// ---- GEMM2: h2[N,40](fp32) = (relu(agg)[N,64] @ W2[64,40]) * dinv[row] ----
__global__ __launch_bounds__(320) void gemm2_kernel(const float* __restrict__ agg,
                                                    const float* __restrict__ W2,
                                                    const float* __restrict__ dinv,
                                                    float* __restrict__ h2) {
  __shared__ float sW[HIDN * NCLS];  // 10 KB
  int tid = threadIdx.x;
  for (int i = tid; i < (HIDN * NCLS) / 4; i += 320)
    ((float4*)sW)[i] = ((const float4*)W2)[i];
  __syncthreads();
  int cg = tid % 10;
  int rp = tid / 10;
  int r0 = blockIdx.x * 64 + rp * 2;
  int r1 = r0 + 1;
  bool v0 = (r0 < NN), v1 = (r1 < NN);
  int c0 = cg * 4;
  float4 a0 = make_float4(0.f, 0.f, 0.f, 0.f);
  float4 a1 = make_float4(0.f, 0.f, 0.f, 0.f);
  const float4* g4 = (const float4*)agg;
  const float4 z4 = make_float4(0.f, 0.f, 0.f, 0.f);
  for (int k0 = 0; k0 < HIDN; k0 += 4) {
    float4 xa = v0 ? g4[(size_t)r0 * 16 + (k0 >> 2)] : z4;
    float4 xb = v1 ? g4[(size_t)r1 * 16 + (k0 >> 2)] : z4;
    xa.x = fmaxf(xa.x, 0.f); xa.y = fmaxf(xa.y, 0.f);
    xa.z = fmaxf(xa.z, 0.f); xa.w = fmaxf(xa.w, 0.f);
    xb.x = fmaxf(xb.x, 0.f); xb.y = fmaxf(xb.y, 0.f);
    xb.z = fmaxf(xb.z, 0.f); xb.w = fmaxf(xb.w, 0.f);
#pragma unroll
    for (int kk = 0; kk < 4; ++kk) {
      float xav = (&xa.x)[kk];
      float xbv = (&xb.x)[kk];
      float4 wv = *(const float4*)&sW[(k0 + kk) * NCLS + c0];
      a0.x += xav * wv.x; a0.y += xav * wv.y; a0.z += xav * wv.z; a0.w += xav * wv.w;
      a1.x += xbv * wv.x; a1.y += xbv * wv.y; a1.z += xbv * wv.z; a1.w += xbv * wv.w;
    }
  }
  if (v0) {
    float di = dinv[r0];
    a0.x *= di; a0.y *= di; a0.z *= di; a0.w *= di;
    *(float4*)&h2[(size_t)r0 * NCLS + c0] = a0;
  }
  if (v1) {
    float di = dinv[r1];
    a1.x *= di; a1.y *= di; a1.z *= di; a1.w *= di;
    *(float4*)&h2[(size_t)r1 * NCLS + c0] = a1;
  }
}

// ---- agg2: out[n,c] = dinv[n]*(h2[n,c] + sum_j h2[s_j,c]) + b2[c] ----
__global__ __launch_bounds__(256) void agg2_kernel(const int* __restrict__ off,
                                                   const int* __restrict__ s_src,
                                                   const float* __restrict__ h2,
                                                   const float* __restrict__ dinv,
                                                   const float* __restrict__ b2,
                                                   float* __restrict__ out) {
  unsigned t = blockIdx.x * 256 + threadIdx.x;
  unsigned n = t / NCLS;
  unsigned c = t - n * NCLS;
  if (n >= NN) return;
  int j0 = off[n], j1 = off[n + 1];
  float acc = h2[(size_t)n * NCLS + c];
  int j = j0;
  for (; j + 1 < j1; j += 2) {
    int s0 = s_src[j], s1 = s_src[j + 1];
    acc += h2[(size_t)s0 * NCLS + c];
    acc += h2[(size_t)s1 * NCLS + c];
  }
  if (j < j1) acc += h2[(size_t)s_src[j] * NCLS + c];
  out[(size_t)n * NCLS + c] = acc * dinv[n] + b2[c];
}

extern "C" void kernel_launch(void* const* d_in, const int* in_sizes, int n_in,
                              void* d_out, int out_size, void* d_ws, size_t ws_size,
                              hipStream_t stream) {
  const float* x  = (const float*)d_in[0];
  const void*  ei = d_in[1];
  const float* W1 = (const float*)d_in[2];
  const float* b1 = (const float*)d_in[3];
  const float* W2 = (const float*)d_in[4];
  const float* b2 = (const float*)d_in[5];
  float* out = (float*)d_out;

  char* w = (char*)d_ws;
  size_t off_b = 0;
  auto carve = [&](size_t bytes) -> void* {
    void* p = w + off_b;
    off_b = (off_b + bytes + 255) & ~(size_t)255;
    return p;
  };
  int*   mat   = (int*)  carve((size_t)NEB * NBUCK * 4);   // 611 KB
  int*   tot   = (int*)  carve((size_t)NBUCK * 4);
  int*   bbase = (int*)  carve((size_t)(NBUCK + 1) * 4);
  int*   offs  = (int*)  carve((size_t)(NN + 1) * 4);
  float* dinv  = (float*)carve((size_t)NN * 4);
  int*   flag  = (int*)  carve(256);
  int*   s_src = (int*)  carve((size_t)NE * 4);
  float* h     = (float*)carve((size_t)NN * HIDN * 4);   // also reused as h2
  float* agg   = (float*)carve((size_t)NN * HIDN * 4);   // also holds bbuf first
  // aliases: bbuf (compact, NE*4 = 6.4 MB) lives in agg's region (dead before
  // agg1 writes agg); h2 lives in h's region (h dead after agg1 reads it)
  uint32* bbuf = (uint32*)agg;
  float*  h2   = h;

  probe_kernel<<<1, 64, 0, stream>>>((const unsigned int*)ei, flag);
  passA_kernel<<<NEB, 256, 0, stream>>>(ei, flag, mat);
  passB1_kernel<<<NBUCK, 512, 0, stream>>>(mat, tot);
  passB2_kernel<<<1, 512, 0, stream>>>(tot, bbase);
  passC_kernel<<<NEB, 256, 0, stream>>>(ei, flag, mat, bbase, bbuf);
  build_kernel<<<NBUCK, 256, 0, stream>>>(bbase, bbuf, offs, dinv, s_src);
  gemm1_kernel<<<(NN + 127) / 128, 256, 0, stream>>>(x, W1, dinv, h);
  agg1_kernel<<<(NN * HIDN) / 256, 256, 0, stream>>>(offs, s_src, h, dinv, b1, agg);
  gemm2_kernel<<<(NN + 63) / 64, 320, 0, stream>>>(agg, W2, dinv, h2);
  agg2_kernel<<<(NN * NCLS + 255) / 256, 256, 0, stream>>>(offs, s_src, h2, dinv, b2, out);
}

// Round 7
// 414.489 us; speedup vs baseline: 2.3046x; 1.0094x over previous
//
#include <hip/hip_runtime.h>
#include <stdint.h>

#define NN    100000
#define FIN   128
#define HIDN  64
#define NCLS  40
#define NE    1600000
#define NBUCK ((NN + 255) / 256)      // 391 buckets of 256 nodes
#define EPB   4096                    // edges per partition block
#define NEB   ((NE + EPB - 1) / EPB)  // 391 partition blocks

typedef unsigned int uint32;

static __device__ __forceinline__ unsigned short f2bf(float f) {
  uint32 u = __float_as_uint(f);
  u = (u + 0x7fffu + ((u >> 16) & 1u)) >> 16;   // RNE
  return (unsigned short)u;
}
static __device__ __forceinline__ uint32 pack2(float lo, float hi) {
  return (uint32)f2bf(lo) | ((uint32)f2bf(hi) << 16);
}
static __device__ __forceinline__ float bf_lo(uint32 v) {
  return __uint_as_float(v << 16);
}
static __device__ __forceinline__ float bf_hi(uint32 v) {
  return __uint_as_float(v & 0xFFFF0000u);
}

// ---- edge dtype probe: int64 (odd u32 words all zero) vs int32 ----
__global__ __launch_bounds__(64) void probe_kernel(const unsigned int* __restrict__ raw,
                                                   int* __restrict__ flag) {
  if (threadIdx.x == 0) {
    int is64 = 1;
    for (int i = 0; i < 64; ++i)
      if (raw[2 * i + 1] != 0u) { is64 = 0; break; }
    *flag = is64;
  }
}

// ---- passA: per-block bucket histogram -> mat[blk][bucket] ----
__global__ __launch_bounds__(256) void passA_kernel(const void* __restrict__ eptr,
                                                    const int* __restrict__ flag,
                                                    int* __restrict__ mat) {
  __shared__ int cnt[NBUCK];
  int tid = threadIdx.x;
  for (int i = tid; i < NBUCK; i += 256) cnt[i] = 0;
  __syncthreads();
  int is64 = *flag;
  int base = blockIdx.x * EPB;
#pragma unroll
  for (int k = 0; k < EPB / 256; ++k) {
    int e = base + k * 256 + tid;
    if (e < NE) {
      int d = is64 ? (int)((const long long*)eptr)[e + NE]
                   : ((const int*)eptr)[e + NE];
      atomicAdd(&cnt[d >> 8], 1);
    }
  }
  __syncthreads();
  for (int i = tid; i < NBUCK; i += 256)
    mat[blockIdx.x * NBUCK + i] = cnt[i];
}

// ---- passB1: per-bucket exclusive scan over blocks; emit bucket totals ----
__global__ __launch_bounds__(512) void passB1_kernel(int* __restrict__ mat,
                                                     int* __restrict__ tot) {
  __shared__ int s[512];
  int b = blockIdx.x;         // bucket
  int t = threadIdx.x;        // block index
  int v = (t < NEB) ? mat[t * NBUCK + b] : 0;
  s[t] = v;
  __syncthreads();
#pragma unroll
  for (int d = 1; d < 512; d <<= 1) {
    int u = (t >= d) ? s[t - d] : 0;
    __syncthreads();
    s[t] += u;
    __syncthreads();
  }
  if (t < NEB) mat[t * NBUCK + b] = s[t] - v;  // exclusive prefix within bucket
  if (t == 511) tot[b] = s[511];
}

// ---- passB2: exclusive scan of bucket totals -> bbase ----
__global__ __launch_bounds__(512) void passB2_kernel(const int* __restrict__ tot,
                                                     int* __restrict__ bbase) {
  __shared__ int s[512];
  int i = threadIdx.x;
  int v = (i < NBUCK) ? tot[i] : 0;
  s[i] = v;
  __syncthreads();
#pragma unroll
  for (int d = 1; d < 512; d <<= 1) {
    int u = (i >= d) ? s[i - d] : 0;
    __syncthreads();
    s[i] += u;
    __syncthreads();
  }
  if (i < NBUCK) bbase[i] = s[i] - v;
  if (i == 511) bbase[NBUCK] = s[511];
}

// ---- passC: place edges into compact bucket-sorted bbuf (LDS cursors) ----
__global__ __launch_bounds__(256) void passC_kernel(const void* __restrict__ eptr,
                                                    const int* __restrict__ flag,
                                                    const int* __restrict__ mat,
                                                    const int* __restrict__ bbase,
                                                    uint32* __restrict__ bbuf) {
  __shared__ int cur[NBUCK];
  int tid = threadIdx.x;
  for (int i = tid; i < NBUCK; i += 256)
    cur[i] = bbase[i] + mat[blockIdx.x * NBUCK + i];
  __syncthreads();
  int is64 = *flag;
  int base = blockIdx.x * EPB;
#pragma unroll
  for (int k = 0; k < EPB / 256; ++k) {
    int e = base + k * 256 + tid;
    if (e < NE) {
      int s, d;
      if (is64) {
        const long long* p = (const long long*)eptr;
        s = (int)p[e]; d = (int)p[e + NE];
      } else {
        const int* p = (const int*)eptr;
        s = p[e]; d = p[e + NE];
      }
      int slot = atomicAdd(&cur[d >> 8], 1);
      bbuf[slot] = (uint32)s | ((uint32)(d & 255) << 17);
    }
  }
}

// ---- build: per-bucket CSR (LDS hist + scan + rank placement) ----
__global__ __launch_bounds__(256) void build_kernel(const int* __restrict__ bbase,
                                                    const uint32* __restrict__ bbuf,
                                                    int* __restrict__ off,
                                                    float* __restrict__ dinv,
                                                    int* __restrict__ s_src) {
  __shared__ int hist[256];
  __shared__ int lofs[256];
  __shared__ int rank[256];
  int b = blockIdx.x, tid = threadIdx.x;
  int base = bbase[b];
  int count = bbase[b + 1] - base;
  const uint32* p = bbuf + base;
  hist[tid] = 0;
  __syncthreads();
  for (int i = tid; i < count; i += 256) atomicAdd(&hist[p[i] >> 17], 1);
  __syncthreads();
  int deg = hist[tid];
  lofs[tid] = deg;
  __syncthreads();
#pragma unroll
  for (int dd = 1; dd < 256; dd <<= 1) {
    int t = (tid >= dd) ? lofs[tid - dd] : 0;
    __syncthreads();
    lofs[tid] += t;
    __syncthreads();
  }
  int excl = lofs[tid] - deg;
  __syncthreads();
  lofs[tid] = excl;
  rank[tid] = 0;
  int n = b * 256 + tid;
  if (n < NN) {
    off[n] = base + excl;
    dinv[n] = rsqrtf((float)deg + 1.0f);
  }
  if (b == 0 && tid == 0) off[NN] = NE;
  __syncthreads();
  for (int i = tid; i < count; i += 256) {
    uint32 v = p[i];
    int dl = (int)(v >> 17);
    int s = (int)(v & 0x1FFFFu);
    int r = atomicAdd(&rank[dl], 1);
    s_src[base + lofs[dl] + r] = s;
  }
}

// ---- GEMM1: hs[N,64](bf16) = (x[N,128] @ W1[128,64]) * dinv[row] ----
// bf16 epilogue: uint4 stores, contiguous lines per wave (proven safe in R3).
__global__ __launch_bounds__(256) void gemm1_kernel(const float* __restrict__ x,
                                                    const float* __restrict__ W,
                                                    const float* __restrict__ dinv,
                                                    uint32* __restrict__ hs) {
  __shared__ float sW[FIN * HIDN];  // 32 KB
  int tid = threadIdx.x;
  {
    const float4* W4 = (const float4*)W;
    float4* sW4 = (float4*)sW;
#pragma unroll
    for (int i = 0; i < 8; ++i) sW4[i * 256 + tid] = W4[i * 256 + tid];
  }
  __syncthreads();
  int cg = tid & 3;
  int rp = tid >> 2;
  int r0 = blockIdx.x * 128 + rp * 2;
  int r1 = r0 + 1;
  bool v0 = (r0 < NN), v1 = (r1 < NN);
  int c0 = cg * 16;
  float4 a0[4], a1[4];
#pragma unroll
  for (int j = 0; j < 4; ++j) {
    a0[j] = make_float4(0.f, 0.f, 0.f, 0.f);
    a1[j] = make_float4(0.f, 0.f, 0.f, 0.f);
  }
  const float4* x4 = (const float4*)x;
  const float4 z4 = make_float4(0.f, 0.f, 0.f, 0.f);
  for (int k0 = 0; k0 < FIN; k0 += 4) {
    float4 xa = v0 ? x4[(size_t)r0 * 32 + (k0 >> 2)] : z4;
    float4 xb = v1 ? x4[(size_t)r1 * 32 + (k0 >> 2)] : z4;
#pragma unroll
    for (int kk = 0; kk < 4; ++kk) {
      float xav = (&xa.x)[kk];
      float xbv = (&xb.x)[kk];
      int k = k0 + kk;
#pragma unroll
      for (int j = 0; j < 4; ++j) {
        float4 wv = *(const float4*)&sW[k * HIDN + c0 + 4 * j];
        a0[j].x += xav * wv.x; a0[j].y += xav * wv.y;
        a0[j].z += xav * wv.z; a0[j].w += xav * wv.w;
        a1[j].x += xbv * wv.x; a1[j].y += xbv * wv.y;
        a1[j].z += xbv * wv.z; a1[j].w += xbv * wv.w;
      }
    }
  }
  if (v0) {
    float di = dinv[r0];
    uint4 q0, q1;
    q0.x = pack2(a0[0].x * di, a0[0].y * di); q0.y = pack2(a0[0].z * di, a0[0].w * di);
    q0.z = pack2(a0[1].x * di, a0[1].y * di); q0.w = pack2(a0[1].z * di, a0[1].w * di);
    q1.x = pack2(a0[2].x * di, a0[2].y * di); q1.y = pack2(a0[2].z * di, a0[2].w * di);
    q1.z = pack2(a0[3].x * di, a0[3].y * di); q1.w = pack2(a0[3].z * di, a0[3].w * di);
    uint4* hp = (uint4*)&hs[(size_t)r0 * 32 + cg * 8];
    hp[0] = q0; hp[1] = q1;
  }
  if (v1) {
    float di = dinv[r1];
    uint4 q0, q1;
    q0.x = pack2(a1[0].x * di, a1[0].y * di); q0.y = pack2(a1[0].z * di, a1[0].w * di);
    q0.z = pack2(a1[1].x * di, a1[1].y * di); q0.w = pack2(a1[1].z * di, a1[1].w * di);
    q1.x = pack2(a1[2].x * di, a1[2].y * di); q1.y = pack2(a1[2].z * di, a1[2].w * di);
    q1.z = pack2(a1[3].x * di, a1[3].y * di); q1.w = pack2(a1[3].z * di, a1[3].w * di);
    uint4* hp = (uint4*)&hs[(size_t)r1 * 32 + cg * 8];
    hp[0] = q0; hp[1] = q1;
  }
}

// ---- agg1: one wave per node; lane = 2 bf16 cols; halves take alternate edges.
// agg[n,c] = dinv[n]*(hs[n,c] + sum_j hs[s_j,c]) + b1[c]  (fp32 out) ----
__global__ __launch_bounds__(256) void agg1_kernel(const int* __restrict__ off,
                                                   const int* __restrict__ s_src,
                                                   const uint32* __restrict__ hs,
                                                   const float* __restrict__ dinv,
                                                   const float* __restrict__ b1,
                                                   float* __restrict__ agg) {
  int n = blockIdx.x * 4 + (threadIdx.x >> 6);     // NN = 25000*4 exactly
  int lane = threadIdx.x & 63;
  int half = lane >> 5;        // 0: even edges, 1: odd edges
  int hc = lane & 31;          // column pair index (cols 2hc, 2hc+1)
  int j0 = off[n], j1 = off[n + 1];
  float ax = 0.f, ay = 0.f;
  if (half == 0) {             // self term counted once
    uint32 v = hs[(size_t)n * 32 + hc];
    ax = bf_lo(v); ay = bf_hi(v);
  }
  for (int j = j0 + half; j < j1; j += 2) {
    int s = s_src[j];
    uint32 v = hs[(size_t)s * 32 + hc];
    ax += bf_lo(v); ay += bf_hi(v);
  }
  // combine the two halves (each lane pairs with lane^32, same hc)
  ax += __shfl_xor(ax, 32, 64);
  ay += __shfl_xor(ay, 32, 64);
  if (half == 0) {
    float di = dinv[n];
    float2 bb = ((const float2*)b1)[hc];
    float2 r;
    r.x = ax * di + bb.x;
    r.y = ay * di + bb.y;
    ((float2*)agg)[(size_t)n * 32 + hc] = r;
  }
}

// ---- GEMM2: h2[N,40](fp32) = (relu(agg)[N,64] @ W2[64,40]) * dinv[row] ----
__global__ __launch_bounds__(320) void gemm2_kernel(const float* __restrict__ agg,
                                                    const float* __restrict__ W2,
                                                    const float* __restrict__ dinv,
                                                    float* __restrict__ h2) {
  __shared__ float sW[HIDN * NCLS];  // 10 KB
  int tid = threadIdx.x;
  for (int i = tid; i < (HIDN * NCLS) / 4; i += 320)
    ((float4*)sW)[i] = ((const float4*)W2)[i];
  __syncthreads();
  int cg = tid % 10;
  int rp = tid / 10;
  int r0 = blockIdx.x * 64 + rp * 2;
  int r1 = r0 + 1;
  bool v0 = (r0 < NN), v1 = (r1 < NN);
  int c0 = cg * 4;
  float4 a0 = make_float4(0.f, 0.f, 0.f, 0.f);
  float4 a1 = make_float4(0.f, 0.f, 0.f, 0.f);
  const float4* g4 = (const float4*)agg;
  const float4 z4 = make_float4(0.f, 0.f, 0.f, 0.f);
  for (int k0 = 0; k0 < HIDN; k0 += 4) {
    float4 xa = v0 ? g4[(size_t)r0 * 16 + (k0 >> 2)] : z4;
    float4 xb = v1 ? g4[(size_t)r1 * 16 + (k0 >> 2)] : z4;
    xa.x = fmaxf(xa.x, 0.f); xa.y = fmaxf(xa.y, 0.f);
    xa.z = fmaxf(xa.z, 0.f); xa.w = fmaxf(xa.w, 0.f);
    xb.x = fmaxf(xb.x, 0.f); xb.y = fmaxf(xb.y, 0.f);
    xb.z = fmaxf(xb.z, 0.f); xb.w = fmaxf(xb.w, 0.f);
#pragma unroll
    for (int kk = 0; kk < 4; ++kk) {
      float xav = (&xa.x)[kk];
      float xbv = (&xb.x)[kk];
      float4 wv = *(const float4*)&sW[(k0 + kk) * NCLS + c0];
      a0.x += xav * wv.x; a0.y += xav * wv.y; a0.z += xav * wv.z; a0.w += xav * wv.w;
      a1.x += xbv * wv.x; a1.y += xbv * wv.y; a1.z += xbv * wv.z; a1.w += xbv * wv.w;
    }
  }
  if (v0) {
    float di = dinv[r0];
    a0.x *= di; a0.y *= di; a0.z *= di; a0.w *= di;
    *(float4*)&h2[(size_t)r0 * NCLS + c0] = a0;
  }
  if (v1) {
    float di = dinv[r1];
    a1.x *= di; a1.y *= di; a1.z *= di; a1.w *= di;
    *(float4*)&h2[(size_t)r1 * NCLS + c0] = a1;
  }
}

// ---- agg2: out[n,c] = dinv[n]*(h2[n,c] + sum_j h2[s_j,c]) + b2[c] ----
__global__ __launch_bounds__(256) void agg2_kernel(const int* __restrict__ off,
                                                   const int* __restrict__ s_src,
                                                   const float* __restrict__ h2,
                                                   const float* __restrict__ dinv,
                                                   const float* __restrict__ b2,
                                                   float* __restrict__ out) {
  unsigned t = blockIdx.x * 256 + threadIdx.x;
  unsigned n = t / NCLS;
  unsigned c = t - n * NCLS;
  if (n >= NN) return;
  int j0 = off[n], j1 = off[n + 1];
  float acc = h2[(size_t)n * NCLS + c];
  int j = j0;
  for (; j + 1 < j1; j += 2) {
    int s0 = s_src[j], s1 = s_src[j + 1];
    acc += h2[(size_t)s0 * NCLS + c];
    acc += h2[(size_t)s1 * NCLS + c];
  }
  if (j < j1) acc += h2[(size_t)s_src[j] * NCLS + c];
  out[(size_t)n * NCLS + c] = acc * dinv[n] + b2[c];
}

extern "C" void kernel_launch(void* const* d_in, const int* in_sizes, int n_in,
                              void* d_out, int out_size, void* d_ws, size_t ws_size,
                              hipStream_t stream) {
  const float* x  = (const float*)d_in[0];
  const void*  ei = d_in[1];
  const float* W1 = (const float*)d_in[2];
  const float* b1 = (const float*)d_in[3];
  const float* W2 = (const float*)d_in[4];
  const float* b2 = (const float*)d_in[5];
  float* out = (float*)d_out;

  char* w = (char*)d_ws;
  size_t off_b = 0;
  auto carve = [&](size_t bytes) -> void* {
    void* p = w + off_b;
    off_b = (off_b + bytes + 255) & ~(size_t)255;
    return p;
  };
  int*    mat   = (int*)   carve((size_t)NEB * NBUCK * 4);   // 611 KB
  int*    tot   = (int*)   carve((size_t)NBUCK * 4);
  int*    bbase = (int*)   carve((size_t)(NBUCK + 1) * 4);
  int*    offs  = (int*)   carve((size_t)(NN + 1) * 4);
  float*  dinv  = (float*) carve((size_t)NN * 4);
  int*    flag  = (int*)   carve(256);
  int*    s_src = (int*)   carve((size_t)NE * 4);
  uint32* hs    = (uint32*)carve((size_t)NN * 32 * 4);       // bf16 h, 12.8 MB
  float*  agg   = (float*) carve((size_t)NN * HIDN * 4);     // 25.6 MB (bbuf first)
  float*  h2    = (float*) carve((size_t)NN * NCLS * 4);     // 16 MB
  // alias: bbuf (compact, NE*4 = 6.4 MB) lives in agg's region (dead before
  // agg1 writes agg)
  uint32* bbuf = (uint32*)agg;

  probe_kernel<<<1, 64, 0, stream>>>((const unsigned int*)ei, flag);
  passA_kernel<<<NEB, 256, 0, stream>>>(ei, flag, mat);
  passB1_kernel<<<NBUCK, 512, 0, stream>>>(mat, tot);
  passB2_kernel<<<1, 512, 0, stream>>>(tot, bbase);
  passC_kernel<<<NEB, 256, 0, stream>>>(ei, flag, mat, bbase, bbuf);
  build_kernel<<<NBUCK, 256, 0, stream>>>(bbase, bbuf, offs, dinv, s_src);
  gemm1_kernel<<<(NN + 127) / 128, 256, 0, stream>>>(x, W1, dinv, hs);
  agg1_kernel<<<NN / 4, 256, 0, stream>>>(offs, s_src, hs, dinv, b1, agg);
  gemm2_kernel<<<(NN + 63) / 64, 320, 0, stream>>>(agg, W2, dinv, h2);
  agg2_kernel<<<(NN * NCLS + 255) / 256, 256, 0, stream>>>(offs, s_src, h2, dinv, b2, out);
}